// Round 9
// baseline (200.850 us; speedup 1.0000x reference)
//
#include <hip/hip_runtime.h>

#define NUM_CODES 512
#define DIM 64
#define NPIX (32 * 64 * 64)  // 131072 pixels
#define BLK 512              // 8 waves: 0-3 = code half 0, 4-7 = half 1
#define NGRP 4               // pixel groups per wave (16 px each) -> 64 px/wave
#define PPB 256              // pixels per block
#define NPH 4                // staging phases
#define LTPP 4               // local tiles (16 codes) per half per phase

typedef __attribute__((ext_vector_type(8))) short bf16x8;
typedef __attribute__((ext_vector_type(4))) float f32x4;

__device__ __forceinline__ unsigned short f2bf(float f) {
    unsigned u = __float_as_uint(f);
    return (unsigned short)((u + 0x7fffu + ((u >> 16) & 1u)) >> 16);
}
__device__ __forceinline__ float bf2f(unsigned short h) {
    return __uint_as_float(((unsigned)h) << 16);
}

// ---------------------------------------------------------------------------
// Prep: swizzle codebook into bf16 hi/lo A-fragment order + exact l2e.
// A-frag (16x16x32): lane = (k_in_32/8)*16 + m, elem j = k%8.
// AH/ALO layout: [gt][s][lane][8] -> 1 KB per (gt,s).
// ---------------------------------------------------------------------------
__global__ __launch_bounds__(256) void prep_kernel(
    const float* __restrict__ emb, unsigned short* __restrict__ AH,
    unsigned short* __restrict__ ALO, float* __restrict__ l2e,
    float* __restrict__ l2eh) {
    const int t = blockIdx.x * 256 + threadIdx.x;  // 0..8191
    const int e0 = t * 4;
    const int c = e0 >> 6, d0 = e0 & 63;
    const float4 v = *(const float4*)(emb + c * DIM + d0);
    float f[4] = {v.x, v.y, v.z, v.w};
    unsigned short h[4], l[4];
#pragma unroll
    for (int i = 0; i < 4; ++i) {
        h[i] = f2bf(f[i]);
        l[i] = f2bf(f[i] - bf2f(h[i]));
    }
    const int ct = c >> 4, mr = c & 15, s = d0 >> 5, q = (d0 & 31) >> 3,
              j0 = d0 & 7;
    const int base = ((ct * 2 + s) * 64 + (q * 16 + mr)) * 8 + j0;
    *(ushort4*)(AH + base) = make_ushort4(h[0], h[1], h[2], h[3]);
    *(ushort4*)(ALO + base) = make_ushort4(l[0], l[1], l[2], l[3]);

    if (t < NUM_CODES) {  // exact ||e||^2, validated pairwise-8 order
        const float* e = emb + t * DIM;
        float r[8];
#pragma unroll
        for (int j = 0; j < 8; ++j) {
            float w = e[j];
            r[j] = w * w;
        }
#pragma unroll
        for (int i = 8; i < DIM; i += 8)
#pragma unroll
            for (int j = 0; j < 8; ++j) {
                float w = e[i + j];
                r[j] += w * w;
            }
        float sv =
            ((r[0] + r[1]) + (r[2] + r[3])) + ((r[4] + r[5]) + (r[6] + r[7]));
        l2e[t] = sv;
        l2eh[t] = 0.5f * sv;
    }
}

// ---------------------------------------------------------------------------
// Main: 8 waves / 256 px / 2 blocks/CU. 4 phases: stage 32 KB of A-frags
// (128 codes, hi+lo) into LDS, then wave w scans its half's 4 staged tiles
// for its 64 px (wgrp = w&3) via ds_read_b128. Selection/merge/refine/gather
// identical to the validated R7 logic.
// ---------------------------------------------------------------------------
__global__ __launch_bounds__(BLK, 4) void vq_main(
    const float* __restrict__ x_in, const uint4* __restrict__ AH4,
    const uint4* __restrict__ ALO4, const float* __restrict__ l2e,
    const float* __restrict__ l2eh, const float* __restrict__ emb,
    float* __restrict__ codes_out, float* __restrict__ vecs_out) {
    // stage buffer: 32 chunks of 1 KB; chunk = (((h*4+lt)*2+s)*2)+hilo
    __shared__ uint4 s_A4[32 * 64];  // 32 KB
    __shared__ float s_l2eh[NUM_CODES];
    __shared__ float s_l2ex[NUM_CODES];
    __shared__ float s_d1h[2][PPB];
    __shared__ float s_d2h[2][PPB];
    __shared__ int s_k1h[2][PPB];
    __shared__ int s_k2h[2][PPB];
    __shared__ float s_dbuf[PPB];
    __shared__ int s_code[PPB];

    const int tid = threadIdx.x, lane = tid & 63, wave = tid >> 6;
    const int wgrp = wave & 3, whalf = wave >> 2;
    s_l2eh[tid] = l2eh[tid];
    s_l2ex[tid] = l2e[tid];

    const int p = lane & 15, q = lane >> 4;
    const int pw = blockIdx.x * PPB + wgrp * (16 * NGRP);  // wave's 64 px

    // ---- B fragments for 4 groups: B[k][n]: n=lane&15, k=(lane>>4)*8+j ----
    bf16x8 bh0[NGRP], bl0[NGRP], bh1[NGRP], bl1[NGRP];
#pragma unroll
    for (int g = 0; g < NGRP; ++g) {
        const float* xb = x_in + (size_t)(pw + g * 16 + p) * DIM + q * 8;
        float4 u0 = *(const float4*)(xb);
        float4 u1 = *(const float4*)(xb + 4);
        float4 u2 = *(const float4*)(xb + 32);
        float4 u3 = *(const float4*)(xb + 36);
        float f0[8] = {u0.x, u0.y, u0.z, u0.w, u1.x, u1.y, u1.z, u1.w};
        float f1[8] = {u2.x, u2.y, u2.z, u2.w, u3.x, u3.y, u3.z, u3.w};
#pragma unroll
        for (int j = 0; j < 8; ++j) {
            unsigned short hh = f2bf(f0[j]);
            bh0[g][j] = (short)hh;
            bl0[g][j] = (short)f2bf(f0[j] - bf2f(hh));
            unsigned short h2 = f2bf(f1[j]);
            bh1[g][j] = (short)h2;
            bl1[g][j] = (short)f2bf(f1[j] - bf2f(h2));
        }
    }

    const int rowbase = q * 4;  // C/D: row = (lane>>4)*4 + reg
    float d1[NGRP], d2[NGRP];
    int k1[NGRP], k2[NGRP];
#pragma unroll
    for (int g = 0; g < NGRP; ++g) {
        d1[g] = 3.4e38f;
        d2[g] = 3.4e38f;
        k1[g] = 0;
        k2[g] = 0;
    }

    for (int ph = 0; ph < NPH; ++ph) {
        __syncthreads();  // previous phase's reads done (and l2 tables ready)
        // ---- stage 32 KB: 2048 uint4, 512 threads x 4 ----
#pragma unroll
        for (int i = 0; i < 4; ++i) {
            const int idx = i * 512 + tid;       // uint4 index in stage
            const int chunk = idx >> 6;          // 0..31 (1 KB chunks)
            const int within = idx & 63;
            const int hilo = chunk & 1;
            const int s = (chunk >> 1) & 1;
            const int lt = (chunk >> 2) & 3;
            const int hh = (chunk >> 4) & 1;
            const int gt = hh * 16 + ph * LTPP + lt;
            const uint4* src = hilo ? ALO4 : AH4;
            s_A4[idx] = src[(gt * 2 + s) * 64 + within];
        }
        __syncthreads();

        // ---- scan this phase's 4 tiles for my half ----
#pragma unroll
        for (int lt = 0; lt < LTPP; ++lt) {
            const int cb = ((whalf * 4 + lt) * 2) * 2 * 64;  // chunk base u4
            const bf16x8 a0h = *(const bf16x8*)&s_A4[cb + lane];
            const bf16x8 a0l = *(const bf16x8*)&s_A4[cb + 64 + lane];
            const bf16x8 a1h = *(const bf16x8*)&s_A4[cb + 128 + lane];
            const bf16x8 a1l = *(const bf16x8*)&s_A4[cb + 192 + lane];
            const int gt = whalf * 16 + ph * LTPP + lt;
            const int kb = gt * 16 + rowbase;
            float l2v[4];
#pragma unroll
            for (int r = 0; r < 4; ++r) l2v[r] = s_l2eh[kb + r];

#pragma unroll
            for (int g = 0; g < NGRP; ++g) {
                f32x4 acc = {0.f, 0.f, 0.f, 0.f};
                acc = __builtin_amdgcn_mfma_f32_16x16x32_bf16(a0h, bh0[g], acc, 0, 0, 0);
                acc = __builtin_amdgcn_mfma_f32_16x16x32_bf16(a1h, bh1[g], acc, 0, 0, 0);
                acc = __builtin_amdgcn_mfma_f32_16x16x32_bf16(a0l, bh0[g], acc, 0, 0, 0);
                acc = __builtin_amdgcn_mfma_f32_16x16x32_bf16(a1l, bh1[g], acc, 0, 0, 0);
                acc = __builtin_amdgcn_mfma_f32_16x16x32_bf16(a0h, bl0[g], acc, 0, 0, 0);
                acc = __builtin_amdgcn_mfma_f32_16x16x32_bf16(a1h, bl1[g], acc, 0, 0, 0);

#pragma unroll
                for (int r = 0; r < 4; ++r) {
                    const float d = l2v[r] - acc[r];
                    const int kk = kb + r;
                    const bool c = d < d1[g], c2 = d < d2[g];
                    const float nd2 = c2 ? d : d2[g];
                    const int nk2 = c2 ? kk : k2[g];
                    d2[g] = c ? d1[g] : nd2;
                    k2[g] = c ? k1[g] : nk2;
                    k1[g] = c ? kk : k1[g];
                    d1[g] = c ? d : d1[g];
                }
            }
        }
    }

    // ---- cross-lane top-2 merge (lanes l, l^16, l^32 share pixel col) ----
#pragma unroll
    for (int g = 0; g < NGRP; ++g) {
        float a1 = d1[g], a2 = d2[g];
        int b1 = k1[g], b2 = k2[g];
#pragma unroll
        for (int off = 16; off <= 32; off <<= 1) {
            const float od1 = __shfl_xor(a1, off);
            const int ok1 = __shfl_xor(b1, off);
            const float od2 = __shfl_xor(a2, off);
            const int ok2 = __shfl_xor(b2, off);
            const bool c = od1 < a1;
            const float w1 = c ? od1 : a1;
            const int wk1 = c ? ok1 : b1;
            const float l1 = c ? a1 : od1;
            const int lk1 = c ? b1 : ok1;
            const bool cm = od2 < a2;
            const float m2 = cm ? od2 : a2;
            const int mk2 = cm ? ok2 : b2;
            const bool c3 = m2 < l1;
            a2 = c3 ? m2 : l1;
            b2 = c3 ? mk2 : lk1;
            a1 = w1;
            b1 = wk1;
        }
        if (lane < 16) {
            const int pb = wgrp * 64 + g * 16 + lane;
            s_d1h[whalf][pb] = a1;
            s_k1h[whalf][pb] = b1;
            s_d2h[whalf][pb] = a2;
            s_k2h[whalf][pb] = b2;
        }
    }
    __syncthreads();

    // ---- merge halves -> (ka,kb), then exact refine split across halves ----
    const int pp = tid & 255;
    const int pix = blockIdx.x * PPB + pp;
    int ka, kb;
    {
        const float d1a = s_d1h[0][pp], d1b = s_d1h[1][pp];
        const float d2a = s_d2h[0][pp], d2b = s_d2h[1][pp];
        const int k1a = s_k1h[0][pp], k1b = s_k1h[1][pp];
        const int k2a = s_k2h[0][pp], k2b = s_k2h[1][pp];
        const bool bw = d1b < d1a;  // tie -> half 0 (lower codes)
        const int bestk = bw ? k1b : k1a;
        const float w2 = bw ? d2b : d2a;
        const int wk2 = bw ? k2b : k2a;
        const float lo1 = bw ? d1a : d1b;
        const int lok1 = bw ? k1a : k1b;
        const bool c2 = (w2 < lo1) || (w2 == lo1 && wk2 < lok1);
        const int k2nd = c2 ? wk2 : lok1;
        ka = bestk;
        kb = k2nd;
        if (kb < ka) {
            const int t = ka;
            ka = kb;
            kb = t;
        }
    }
    // distance of my candidate (validated R0 arithmetic)
    {
        const int myk = (tid < 256) ? ka : kb;
        const float* xr = x_in + (size_t)pix * DIM;
        float x[DIM];
#pragma unroll
        for (int jj = 0; jj < 16; ++jj) {
            const float4 v = *(const float4*)(xr + jj * 4);
            x[4 * jj + 0] = v.x;
            x[4 * jj + 1] = v.y;
            x[4 * jj + 2] = v.z;
            x[4 * jj + 3] = v.w;
        }
        float r[8];
#pragma unroll
        for (int j = 0; j < 8; ++j) r[j] = x[j] * x[j];
#pragma unroll
        for (int i = 8; i < DIM; i += 8)
#pragma unroll
            for (int j = 0; j < 8; ++j) r[j] += x[i + j] * x[i + j];
        const float l2x =
            ((r[0] + r[1]) + (r[2] + r[3])) + ((r[4] + r[5]) + (r[6] + r[7]));

        const float* er = emb + (size_t)myk * DIM;
        float acc = 0.f;
#pragma unroll
        for (int d = 0; d < DIM; ++d) acc = __builtin_fmaf(x[d], er[d], acc);
        const float dist = (l2x + s_l2ex[myk]) - 2.0f * acc;
        if (tid >= 256) s_dbuf[pp] = dist;  // db (higher-index candidate)
        __syncthreads();
        if (tid < 256) {
            const float da = dist;
            const float db = s_dbuf[pp];
            const int sel = (db < da) ? kb : ka;  // strict '<': lower idx wins
            s_code[pp] = sel;
            codes_out[pix] = (float)sel;
        }
    }
    __syncthreads();

    // ---- coalesced gather: 256 px * 16 float4 = 4096 float4, 8 iters ----
    const float4* emb4 = (const float4*)emb;
    float4* vout4 = (float4*)(vecs_out + (size_t)blockIdx.x * PPB * DIM);
#pragma unroll
    for (int it = 0; it < (PPB * DIM / 4) / BLK; ++it) {
        const int fidx = tid + it * BLK;
        const int ppx = fidx >> 4, dd = fidx & 15;
        vout4[fidx] = emb4[(size_t)s_code[ppx] * (DIM / 4) + dd];
    }
}

extern "C" void kernel_launch(void* const* d_in, const int* in_sizes, int n_in,
                              void* d_out, int out_size, void* d_ws,
                              size_t ws_size, hipStream_t stream) {
    const float* x_in = (const float*)d_in[0];  // [32,64,64,64] fp32
    const float* emb = (const float*)d_in[1];   // [512,64] fp32

    // workspace layout
    unsigned short* AH = (unsigned short*)d_ws;    // 64 KB
    unsigned short* ALO = AH + NUM_CODES * DIM;    // 64 KB
    float* l2e = (float*)(ALO + NUM_CODES * DIM);  // 2 KB
    float* l2eh = l2e + NUM_CODES;                 // 2 KB

    float* codes_out = (float*)d_out;        // NPIX floats (codes as f32)
    float* vecs_out = (float*)d_out + NPIX;  // NPIX*DIM floats

    hipLaunchKernelGGL(prep_kernel, dim3(32), dim3(256), 0, stream, emb, AH,
                       ALO, l2e, l2eh);
    hipLaunchKernelGGL(vq_main, dim3(NPIX / PPB), dim3(BLK), 0, stream, x_in,
                       (const uint4*)AH, (const uint4*)ALO, l2e, l2eh, emb,
                       codes_out, vecs_out);
}

// Round 10
// 129.098 us; speedup vs baseline: 1.5558x; 1.5558x over previous
//
#include <hip/hip_runtime.h>

#define NUM_CODES 512
#define DIM 64
#define NPIX (32 * 64 * 64)  // 131072 pixels
#define CT (NUM_CODES / 16)  // 32 code tiles of 16 codes
#define BLK 256
#define NGRP 2               // pixel groups per wave (16 px each) -> 32 px/wave
#define PPB 128              // pixels per block = 4 waves * 32 px

typedef __attribute__((ext_vector_type(8))) short bf16x8;
typedef __attribute__((ext_vector_type(4))) float f32x4;

__device__ __forceinline__ unsigned short f2bf(float f) {
    unsigned u = __float_as_uint(f);
    return (unsigned short)((u + 0x7fffu + ((u >> 16) & 1u)) >> 16);
}
__device__ __forceinline__ float bf2f(unsigned short h) {
    return __uint_as_float(((unsigned)h) << 16);
}

// ---------------------------------------------------------------------------
// Prep: swizzle codebook into bf16 hi/lo A-fragment order + exact l2e.
// A-frag (16x16x32): lane = (k_in_32/8)*16 + m, elem j = k%8.
// ---------------------------------------------------------------------------
__global__ __launch_bounds__(256) void prep_kernel(
    const float* __restrict__ emb, unsigned short* __restrict__ AH,
    unsigned short* __restrict__ ALO, float* __restrict__ l2e,
    float* __restrict__ l2eh) {
    const int t = blockIdx.x * 256 + threadIdx.x;  // 0..8191
    const int e0 = t * 4;
    const int c = e0 >> 6, d0 = e0 & 63;
    const float4 v = *(const float4*)(emb + c * DIM + d0);
    float f[4] = {v.x, v.y, v.z, v.w};
    unsigned short h[4], l[4];
#pragma unroll
    for (int i = 0; i < 4; ++i) {
        h[i] = f2bf(f[i]);
        l[i] = f2bf(f[i] - bf2f(h[i]));
    }
    const int ct = c >> 4, mr = c & 15, s = d0 >> 5, q = (d0 & 31) >> 3,
              j0 = d0 & 7;
    const int base = ((ct * 2 + s) * 64 + (q * 16 + mr)) * 8 + j0;
    *(ushort4*)(AH + base) = make_ushort4(h[0], h[1], h[2], h[3]);
    *(ushort4*)(ALO + base) = make_ushort4(l[0], l[1], l[2], l[3]);

    if (t < NUM_CODES) {  // exact ||e||^2, validated pairwise-8 order
        const float* e = emb + t * DIM;
        float r[8];
#pragma unroll
        for (int j = 0; j < 8; ++j) {
            float w = e[j];
            r[j] = w * w;
        }
#pragma unroll
        for (int i = 8; i < DIM; i += 8)
#pragma unroll
            for (int j = 0; j < 8; ++j) {
                float w = e[i + j];
                r[j] += w * w;
            }
        float sv =
            ((r[0] + r[1]) + (r[2] + r[3])) + ((r[4] + r[5]) + (r[6] + r[7]));
        l2e[t] = sv;
        l2eh[t] = 0.5f * sv;
    }
}

// ---------------------------------------------------------------------------
// Main: 4 waves / 128 px / 4 blocks per CU. Each wave scans all 32 code
// tiles for its 32 px (2 groups); next tile's A-frags are prefetched into
// registers while the current tile computes (hides L2 latency). Selection /
// merge / exact top-2 refine identical to validated R6 logic.
// ---------------------------------------------------------------------------
__global__ __launch_bounds__(BLK, 4) void vq_main(
    const float* __restrict__ x_in, const unsigned short* __restrict__ AH,
    const unsigned short* __restrict__ ALO, const float* __restrict__ l2e,
    const float* __restrict__ l2eh, const float* __restrict__ emb,
    float* __restrict__ codes_out, float* __restrict__ vecs_out) {
    __shared__ float s_l2eh[NUM_CODES];
    __shared__ float s_l2ex[NUM_CODES];
    __shared__ int s_top[PPB][2];
    __shared__ float s_dbuf[PPB];
    __shared__ int s_code[PPB];

    const int tid = threadIdx.x, lane = tid & 63, wave = tid >> 6;
    s_l2eh[tid] = l2eh[tid];
    s_l2eh[tid + 256] = l2eh[tid + 256];
    s_l2ex[tid] = l2e[tid];
    s_l2ex[tid + 256] = l2e[tid + 256];
    __syncthreads();

    const int p = lane & 15, q = lane >> 4;
    const int pw = blockIdx.x * PPB + wave * (16 * NGRP);  // wave's 32 px

    // ---- B fragments for 2 groups: B[k][n]: n=lane&15, k=(lane>>4)*8+j ----
    bf16x8 bh0[NGRP], bl0[NGRP], bh1[NGRP], bl1[NGRP];
#pragma unroll
    for (int g = 0; g < NGRP; ++g) {
        const float* xb = x_in + (size_t)(pw + g * 16 + p) * DIM + q * 8;
        float4 u0 = *(const float4*)(xb);
        float4 u1 = *(const float4*)(xb + 4);
        float4 u2 = *(const float4*)(xb + 32);
        float4 u3 = *(const float4*)(xb + 36);
        float f0[8] = {u0.x, u0.y, u0.z, u0.w, u1.x, u1.y, u1.z, u1.w};
        float f1[8] = {u2.x, u2.y, u2.z, u2.w, u3.x, u3.y, u3.z, u3.w};
#pragma unroll
        for (int j = 0; j < 8; ++j) {
            unsigned short hh = f2bf(f0[j]);
            bh0[g][j] = (short)hh;
            bl0[g][j] = (short)f2bf(f0[j] - bf2f(hh));
            unsigned short h2 = f2bf(f1[j]);
            bh1[g][j] = (short)h2;
            bl1[g][j] = (short)f2bf(f1[j] - bf2f(h2));
        }
    }

    const int rowbase = q * 4;  // C/D: row = (lane>>4)*4 + reg
    float d1[NGRP], d2[NGRP];
    int k1[NGRP], k2[NGRP];
#pragma unroll
    for (int g = 0; g < NGRP; ++g) {
        d1[g] = 3.4e38f;
        d2[g] = 3.4e38f;
        k1[g] = 0;
        k2[g] = 0;
    }

    const unsigned short* pAH = AH + lane * 8;
    const unsigned short* pAL = ALO + lane * 8;

    // ---- prime tile 0's A-fragments ----
    bf16x8 a0h = *(const bf16x8*)(pAH);
    bf16x8 a0l = *(const bf16x8*)(pAL);
    bf16x8 a1h = *(const bf16x8*)(pAH + 512);
    bf16x8 a1l = *(const bf16x8*)(pAL + 512);

    for (int ct = 0; ct < CT; ++ct) {
        // prefetch next tile (wraps to 0 on last iter; harmless)
        const int nt = (ct + 1) & (CT - 1);
        const bf16x8 n0h = *(const bf16x8*)(pAH + nt * 1024);
        const bf16x8 n0l = *(const bf16x8*)(pAL + nt * 1024);
        const bf16x8 n1h = *(const bf16x8*)(pAH + nt * 1024 + 512);
        const bf16x8 n1l = *(const bf16x8*)(pAL + nt * 1024 + 512);

        const int kb = ct * 16 + rowbase;
        float l2v[4];
#pragma unroll
        for (int r = 0; r < 4; ++r) l2v[r] = s_l2eh[kb + r];

#pragma unroll
        for (int g = 0; g < NGRP; ++g) {
            f32x4 acc = {0.f, 0.f, 0.f, 0.f};
            acc = __builtin_amdgcn_mfma_f32_16x16x32_bf16(a0h, bh0[g], acc, 0, 0, 0);
            acc = __builtin_amdgcn_mfma_f32_16x16x32_bf16(a1h, bh1[g], acc, 0, 0, 0);
            acc = __builtin_amdgcn_mfma_f32_16x16x32_bf16(a0l, bh0[g], acc, 0, 0, 0);
            acc = __builtin_amdgcn_mfma_f32_16x16x32_bf16(a1l, bh1[g], acc, 0, 0, 0);
            acc = __builtin_amdgcn_mfma_f32_16x16x32_bf16(a0h, bl0[g], acc, 0, 0, 0);
            acc = __builtin_amdgcn_mfma_f32_16x16x32_bf16(a1h, bl1[g], acc, 0, 0, 0);

#pragma unroll
            for (int r = 0; r < 4; ++r) {
                const float d = l2v[r] - acc[r];
                const int kk = kb + r;
                const bool c = d < d1[g], c2 = d < d2[g];
                const float nd2 = c2 ? d : d2[g];
                const int nk2 = c2 ? kk : k2[g];
                d2[g] = c ? d1[g] : nd2;
                k2[g] = c ? k1[g] : nk2;
                k1[g] = c ? kk : k1[g];
                d1[g] = c ? d : d1[g];
            }
        }
        a0h = n0h;
        a0l = n0l;
        a1h = n1h;
        a1l = n1l;
    }

    // ---- cross-lane top-2 merge (lanes l, l^16, l^32 share pixel col) ----
#pragma unroll
    for (int g = 0; g < NGRP; ++g) {
        float a1 = d1[g], a2 = d2[g];
        int b1 = k1[g], b2 = k2[g];
#pragma unroll
        for (int off = 16; off <= 32; off <<= 1) {
            const float od1 = __shfl_xor(a1, off);
            const int ok1 = __shfl_xor(b1, off);
            const float od2 = __shfl_xor(a2, off);
            const int ok2 = __shfl_xor(b2, off);
            const bool c = od1 < a1;
            const float w1 = c ? od1 : a1;
            const int wk1 = c ? ok1 : b1;
            const float l1 = c ? a1 : od1;
            const int lk1 = c ? b1 : ok1;
            const bool cm = od2 < a2;
            const float m2 = cm ? od2 : a2;
            const int mk2 = cm ? ok2 : b2;
            const bool c3 = m2 < l1;
            a2 = c3 ? m2 : l1;
            b2 = c3 ? mk2 : lk1;
            a1 = w1;
            b1 = wk1;
        }
        if (lane < 16) {
            const int pb = wave * (16 * NGRP) + g * 16 + lane;
            s_top[pb][0] = b1;
            s_top[pb][1] = b2;
        }
    }
    __syncthreads();

    // ---- exact refine: 1 candidate per thread (256 threads, 128 px x 2),
    //      R0-validated arithmetic, strict '<' with lower index priority ----
    {
        const int pp = tid & (PPB - 1);
        const int cand = tid >> 7;  // 0: lower-index candidate, 1: higher
        const int pix = blockIdx.x * PPB + pp;
        int ka = s_top[pp][0], kb2 = s_top[pp][1];
        if (kb2 < ka) {
            const int t = ka;
            ka = kb2;
            kb2 = t;
        }
        const int myk = cand ? kb2 : ka;

        const float* xr = x_in + (size_t)pix * DIM;
        float x[DIM];
#pragma unroll
        for (int jj = 0; jj < 16; ++jj) {
            const float4 v = *(const float4*)(xr + jj * 4);
            x[4 * jj + 0] = v.x;
            x[4 * jj + 1] = v.y;
            x[4 * jj + 2] = v.z;
            x[4 * jj + 3] = v.w;
        }
        float r[8];
#pragma unroll
        for (int j = 0; j < 8; ++j) r[j] = x[j] * x[j];
#pragma unroll
        for (int i = 8; i < DIM; i += 8)
#pragma unroll
            for (int j = 0; j < 8; ++j) r[j] += x[i + j] * x[i + j];
        const float l2x =
            ((r[0] + r[1]) + (r[2] + r[3])) + ((r[4] + r[5]) + (r[6] + r[7]));

        const float* er = emb + (size_t)myk * DIM;
        float acc = 0.f;
#pragma unroll
        for (int d = 0; d < DIM; ++d) acc = __builtin_fmaf(x[d], er[d], acc);
        const float dist = (l2x + s_l2ex[myk]) - 2.0f * acc;

        if (cand) s_dbuf[pp] = dist;  // db: higher-index candidate
        __syncthreads();
        if (!cand) {
            const float da = dist;
            const float db = s_dbuf[pp];
            const int sel = (db < da) ? kb2 : ka;  // strict '<': lower wins
            s_code[pp] = sel;
            codes_out[pix] = (float)sel;
        }
    }
    __syncthreads();

    // ---- coalesced gather: 128 px * 16 float4 = 2048 float4, 8 iters ----
    const float4* emb4 = (const float4*)emb;
    float4* vout4 = (float4*)(vecs_out + (size_t)blockIdx.x * PPB * DIM);
#pragma unroll
    for (int it = 0; it < (PPB * DIM / 4) / BLK; ++it) {
        const int fidx = tid + it * BLK;
        const int pp = fidx >> 4, dd = fidx & 15;
        vout4[fidx] = emb4[(size_t)s_code[pp] * (DIM / 4) + dd];
    }
}

extern "C" void kernel_launch(void* const* d_in, const int* in_sizes, int n_in,
                              void* d_out, int out_size, void* d_ws,
                              size_t ws_size, hipStream_t stream) {
    const float* x_in = (const float*)d_in[0];  // [32,64,64,64] fp32
    const float* emb = (const float*)d_in[1];   // [512,64] fp32

    // workspace layout
    unsigned short* AH = (unsigned short*)d_ws;    // 64 KB
    unsigned short* ALO = AH + NUM_CODES * DIM;    // 64 KB
    float* l2e = (float*)(ALO + NUM_CODES * DIM);  // 2 KB
    float* l2eh = l2e + NUM_CODES;                 // 2 KB

    float* codes_out = (float*)d_out;        // NPIX floats (codes as f32)
    float* vecs_out = (float*)d_out + NPIX;  // NPIX*DIM floats

    hipLaunchKernelGGL(prep_kernel, dim3(32), dim3(256), 0, stream, emb, AH,
                       ALO, l2e, l2eh);
    hipLaunchKernelGGL(vq_main, dim3(NPIX / PPB), dim3(BLK), 0, stream, x_in,
                       AH, ALO, l2e, l2eh, emb, codes_out, vecs_out);
}

// Round 11
// 123.803 us; speedup vs baseline: 1.6223x; 1.0428x over previous
//
#include <hip/hip_runtime.h>

#define NUM_CODES 512
#define DIM 64
#define NPIX (32 * 64 * 64)  // 131072 pixels
#define CT (NUM_CODES / 16)  // 32 code tiles of 16 codes
#define BLK 256
#define NGRP 4               // pixel groups per wave (16 px each) -> 64 px/wave
#define PPB 256              // pixels per block = 4 waves * 64 px

typedef __attribute__((ext_vector_type(8))) short bf16x8;
typedef __attribute__((ext_vector_type(4))) float f32x4;

__device__ __forceinline__ unsigned short f2bf(float f) {
    unsigned u = __float_as_uint(f);
    return (unsigned short)((u + 0x7fffu + ((u >> 16) & 1u)) >> 16);
}
__device__ __forceinline__ float bf2f(unsigned short h) {
    return __uint_as_float(((unsigned)h) << 16);
}

// ---------------------------------------------------------------------------
// Prep: swizzle NEGATED codebook into bf16 hi/lo A-fragment order + exact
// l2e + l2e/2. A-frag (16x16x32): lane = (k_in_32/8)*16 + m, elem j = k%8.
// With -e in A and acc initialized to l2e/2, the MFMA output IS the
// selection key  l2e/2 - dot  directly.
// ---------------------------------------------------------------------------
__global__ __launch_bounds__(256) void prep_kernel(
    const float* __restrict__ emb, unsigned short* __restrict__ AH,
    unsigned short* __restrict__ ALO, float* __restrict__ l2e,
    float* __restrict__ l2eh) {
    const int t = blockIdx.x * 256 + threadIdx.x;  // 0..8191
    const int e0 = t * 4;
    const int c = e0 >> 6, d0 = e0 & 63;
    const float4 v = *(const float4*)(emb + c * DIM + d0);
    float f[4] = {-v.x, -v.y, -v.z, -v.w};  // NEGATED
    unsigned short h[4], l[4];
#pragma unroll
    for (int i = 0; i < 4; ++i) {
        h[i] = f2bf(f[i]);
        l[i] = f2bf(f[i] - bf2f(h[i]));
    }
    const int ct = c >> 4, mr = c & 15, s = d0 >> 5, q = (d0 & 31) >> 3,
              j0 = d0 & 7;
    const int base = ((ct * 2 + s) * 64 + (q * 16 + mr)) * 8 + j0;
    *(ushort4*)(AH + base) = make_ushort4(h[0], h[1], h[2], h[3]);
    *(ushort4*)(ALO + base) = make_ushort4(l[0], l[1], l[2], l[3]);

    if (t < NUM_CODES) {  // exact ||e||^2, validated pairwise-8 order
        const float* e = emb + t * DIM;
        float r[8];
#pragma unroll
        for (int j = 0; j < 8; ++j) {
            float w = e[j];
            r[j] = w * w;
        }
#pragma unroll
        for (int i = 8; i < DIM; i += 8)
#pragma unroll
            for (int j = 0; j < 8; ++j) {
                float w = e[i + j];
                r[j] += w * w;
            }
        float sv =
            ((r[0] + r[1]) + (r[2] + r[3])) + ((r[4] + r[5]) + (r[6] + r[7]));
        l2e[t] = sv;
        l2eh[t] = 0.5f * sv;
    }
}

// ---------------------------------------------------------------------------
// Main: 4 waves / 256 px (R6 structure). Per tile: acc initialized with
// l2e/2 (LDS, hidden under MFMA chain), 6 MFMAs with negated codebook give
// the key directly; next tile's A-frags prefetched into registers. Top-2
// insert / cross-lane merge / exact refine identical to validated R6 logic.
// ---------------------------------------------------------------------------
__global__ __launch_bounds__(BLK, 2) void vq_main(
    const float* __restrict__ x_in, const unsigned short* __restrict__ AH,
    const unsigned short* __restrict__ ALO, const float* __restrict__ l2e,
    const float* __restrict__ l2eh, const float* __restrict__ emb,
    float* __restrict__ codes_out, float* __restrict__ vecs_out) {
    __shared__ float s_l2eh[NUM_CODES];
    __shared__ float s_l2ex[NUM_CODES];
    __shared__ int s_top[PPB][2];
    __shared__ int s_code[PPB];

    const int tid = threadIdx.x, lane = tid & 63, wave = tid >> 6;
    s_l2eh[tid] = l2eh[tid];
    s_l2eh[tid + 256] = l2eh[tid + 256];
    s_l2ex[tid] = l2e[tid];
    s_l2ex[tid + 256] = l2e[tid + 256];
    __syncthreads();

    const int p = lane & 15, q = lane >> 4;
    const int pw = blockIdx.x * PPB + wave * (16 * NGRP);  // wave's 64 px

    // ---- B fragments for 4 groups: B[k][n]: n=lane&15, k=(lane>>4)*8+j ----
    bf16x8 bh0[NGRP], bl0[NGRP], bh1[NGRP], bl1[NGRP];
#pragma unroll
    for (int g = 0; g < NGRP; ++g) {
        const float* xb = x_in + (size_t)(pw + g * 16 + p) * DIM + q * 8;
        float4 u0 = *(const float4*)(xb);
        float4 u1 = *(const float4*)(xb + 4);
        float4 u2 = *(const float4*)(xb + 32);
        float4 u3 = *(const float4*)(xb + 36);
        float f0[8] = {u0.x, u0.y, u0.z, u0.w, u1.x, u1.y, u1.z, u1.w};
        float f1[8] = {u2.x, u2.y, u2.z, u2.w, u3.x, u3.y, u3.z, u3.w};
#pragma unroll
        for (int j = 0; j < 8; ++j) {
            unsigned short hh = f2bf(f0[j]);
            bh0[g][j] = (short)hh;
            bl0[g][j] = (short)f2bf(f0[j] - bf2f(hh));
            unsigned short h2 = f2bf(f1[j]);
            bh1[g][j] = (short)h2;
            bl1[g][j] = (short)f2bf(f1[j] - bf2f(h2));
        }
    }

    const int rowbase = q * 4;  // C/D: row = (lane>>4)*4 + reg
    float d1[NGRP], d2[NGRP];
    int k1[NGRP], k2[NGRP];
#pragma unroll
    for (int g = 0; g < NGRP; ++g) {
        d1[g] = 3.4e38f;
        d2[g] = 3.4e38f;
        k1[g] = 0;
        k2[g] = 0;
    }

    const unsigned short* pAH = AH + lane * 8;
    const unsigned short* pAL = ALO + lane * 8;

    // ---- prime tile 0's A-fragments ----
    bf16x8 a0h = *(const bf16x8*)(pAH);
    bf16x8 a0l = *(const bf16x8*)(pAL);
    bf16x8 a1h = *(const bf16x8*)(pAH + 512);
    bf16x8 a1l = *(const bf16x8*)(pAL + 512);

    for (int ct = 0; ct < CT; ++ct) {
        // prefetch next tile (wraps to 0 on last iter; harmless)
        const int nt = (ct + 1) & (CT - 1);
        const bf16x8 n0h = *(const bf16x8*)(pAH + nt * 1024);
        const bf16x8 n0l = *(const bf16x8*)(pAL + nt * 1024);
        const bf16x8 n1h = *(const bf16x8*)(pAH + nt * 1024 + 512);
        const bf16x8 n1l = *(const bf16x8*)(pAL + nt * 1024 + 512);

        const int kb = ct * 16 + rowbase;
        // acc-init with l2e/2 (LDS reads issue before the MFMA chain)
        f32x4 acc_init;
#pragma unroll
        for (int r = 0; r < 4; ++r) acc_init[r] = s_l2eh[kb + r];

#pragma unroll
        for (int g = 0; g < NGRP; ++g) {
            f32x4 acc = acc_init;
            acc = __builtin_amdgcn_mfma_f32_16x16x32_bf16(a0h, bh0[g], acc, 0, 0, 0);
            acc = __builtin_amdgcn_mfma_f32_16x16x32_bf16(a1h, bh1[g], acc, 0, 0, 0);
            acc = __builtin_amdgcn_mfma_f32_16x16x32_bf16(a0l, bh0[g], acc, 0, 0, 0);
            acc = __builtin_amdgcn_mfma_f32_16x16x32_bf16(a1l, bh1[g], acc, 0, 0, 0);
            acc = __builtin_amdgcn_mfma_f32_16x16x32_bf16(a0h, bl0[g], acc, 0, 0, 0);
            acc = __builtin_amdgcn_mfma_f32_16x16x32_bf16(a1h, bl1[g], acc, 0, 0, 0);

#pragma unroll
            for (int r = 0; r < 4; ++r) {
                const float d = acc[r];  // = l2e/2 - dot  (key, no sub)
                const int kk = kb + r;
                const bool c = d < d1[g], c2 = d < d2[g];
                const float nd2 = c2 ? d : d2[g];
                const int nk2 = c2 ? kk : k2[g];
                d2[g] = c ? d1[g] : nd2;
                k2[g] = c ? k1[g] : nk2;
                k1[g] = c ? kk : k1[g];
                d1[g] = c ? d : d1[g];
            }
        }
        a0h = n0h;
        a0l = n0l;
        a1h = n1h;
        a1l = n1l;
    }

    // ---- cross-lane top-2 merge (lanes l, l^16, l^32 share pixel col) ----
#pragma unroll
    for (int g = 0; g < NGRP; ++g) {
        float a1 = d1[g], a2 = d2[g];
        int b1 = k1[g], b2 = k2[g];
#pragma unroll
        for (int off = 16; off <= 32; off <<= 1) {
            const float od1 = __shfl_xor(a1, off);
            const int ok1 = __shfl_xor(b1, off);
            const float od2 = __shfl_xor(a2, off);
            const int ok2 = __shfl_xor(b2, off);
            const bool c = od1 < a1;
            const float w1 = c ? od1 : a1;
            const int wk1 = c ? ok1 : b1;
            const float l1 = c ? a1 : od1;
            const int lk1 = c ? b1 : ok1;
            const bool cm = od2 < a2;
            const float m2 = cm ? od2 : a2;
            const int mk2 = cm ? ok2 : b2;
            const bool c3 = m2 < l1;
            a2 = c3 ? m2 : l1;
            b2 = c3 ? mk2 : lk1;
            a1 = w1;
            b1 = wk1;
        }
        if (lane < 16) {
            const int pb = wave * (16 * NGRP) + g * 16 + lane;
            s_top[pb][0] = b1;
            s_top[pb][1] = b2;
        }
    }
    __syncthreads();

    // ---- exact refine of the 2 candidates (R0-validated arithmetic),
    //      one pixel per thread, all 256 threads active ----
    {
        const int pix = blockIdx.x * PPB + tid;
        int ka = s_top[tid][0], kb2 = s_top[tid][1];
        if (kb2 < ka) {
            const int tt = ka;
            ka = kb2;
            kb2 = tt;
        }
        const float* xr = x_in + (size_t)pix * DIM;
        float x[DIM];
#pragma unroll
        for (int jj = 0; jj < 16; ++jj) {
            const float4 v = *(const float4*)(xr + jj * 4);
            x[4 * jj + 0] = v.x;
            x[4 * jj + 1] = v.y;
            x[4 * jj + 2] = v.z;
            x[4 * jj + 3] = v.w;
        }
        float r[8];
#pragma unroll
        for (int j = 0; j < 8; ++j) r[j] = x[j] * x[j];
#pragma unroll
        for (int i = 8; i < DIM; i += 8)
#pragma unroll
            for (int j = 0; j < 8; ++j) r[j] += x[i + j] * x[i + j];
        const float l2x =
            ((r[0] + r[1]) + (r[2] + r[3])) + ((r[4] + r[5]) + (r[6] + r[7]));

        const float* ea = emb + (size_t)ka * DIM;
        float acca = 0.f;
#pragma unroll
        for (int d = 0; d < DIM; ++d) acca = __builtin_fmaf(x[d], ea[d], acca);
        const float da = (l2x + s_l2ex[ka]) - 2.0f * acca;

        const float* eb = emb + (size_t)kb2 * DIM;
        float accb = 0.f;
#pragma unroll
        for (int d = 0; d < DIM; ++d) accb = __builtin_fmaf(x[d], eb[d], accb);
        const float db = (l2x + s_l2ex[kb2]) - 2.0f * accb;

        const int sel = (db < da) ? kb2 : ka;  // strict '<': lower index wins
        s_code[tid] = sel;
        codes_out[pix] = (float)sel;
    }
    __syncthreads();

    // ---- coalesced gather: 256 px * 16 float4 = 4096 float4, 16 iters ----
    const float4* emb4 = (const float4*)emb;
    float4* vout4 = (float4*)(vecs_out + (size_t)blockIdx.x * PPB * DIM);
#pragma unroll
    for (int it = 0; it < (PPB * DIM / 4) / BLK; ++it) {
        const int fidx = tid + it * BLK;
        const int pp = fidx >> 4, dd = fidx & 15;
        vout4[fidx] = emb4[(size_t)s_code[pp] * (DIM / 4) + dd];
    }
}

extern "C" void kernel_launch(void* const* d_in, const int* in_sizes, int n_in,
                              void* d_out, int out_size, void* d_ws,
                              size_t ws_size, hipStream_t stream) {
    const float* x_in = (const float*)d_in[0];  // [32,64,64,64] fp32
    const float* emb = (const float*)d_in[1];   // [512,64] fp32

    // workspace layout
    unsigned short* AH = (unsigned short*)d_ws;    // 64 KB (negated hi)
    unsigned short* ALO = AH + NUM_CODES * DIM;    // 64 KB (negated lo)
    float* l2e = (float*)(ALO + NUM_CODES * DIM);  // 2 KB
    float* l2eh = l2e + NUM_CODES;                 // 2 KB

    float* codes_out = (float*)d_out;        // NPIX floats (codes as f32)
    float* vecs_out = (float*)d_out + NPIX;  // NPIX*DIM floats

    hipLaunchKernelGGL(prep_kernel, dim3(32), dim3(256), 0, stream, emb, AH,
                       ALO, l2e, l2eh);
    hipLaunchKernelGGL(vq_main, dim3(NPIX / PPB), dim3(BLK), 0, stream, x_in,
                       AH, ALO, l2e, l2eh, emb, codes_out, vecs_out);
}